// Round 1
// baseline (387.749 us; speedup 1.0000x reference)
//
#include <hip/hip_runtime.h>
#include <math.h>

// AttentionPool: scores = einsum("btd,d->bt"), masked softmax over T,
// pooled = einsum("bt,btd->bd").  B=16, T=4096, D=1024, f32.
//
// Single-pass online-softmax pooling: read hidden_states exactly once.
// Kernel 1: grid = B*blocksPerB blocks (256 thr = 4 waves). Each wave owns
//   tokensPerWave contiguous tokens; lanes split D (lane holds d = j*256+lane*4,
//   j=0..3 -> 4 x float4, coalesced dwordx4). Wave-reduce dot via shfl_xor,
//   online update (m, l, acc). Cross-wave merge in LDS -> one partial
//   (m, l, acc[1024]) per block into d_ws.
// Kernel 2: per-b combine: global max, rescale partials, normalize, write out.

__global__ __launch_bounds__(256) void ap_partial(
    const float* __restrict__ hs, const int* __restrict__ mask,
    const float* __restrict__ ctx,
    float* __restrict__ accs, float* __restrict__ ms, float* __restrict__ ls,
    int T, int blocksPerB, int tokensPerWave)
{
    const int D = 1024;            // layout assumption: D == 1024 (4*64*4)
    int bi    = blockIdx.x;
    int b     = bi / blocksPerB;
    int chunk = bi - b * blocksPerB;
    int wave  = threadIdx.x >> 6;
    int lane  = threadIdx.x & 63;

    int t0 = chunk * (tokensPerWave * 4) + wave * tokensPerWave;

    // context vector fragment: d = j*256 + lane*4
    const float4* ctx4 = (const float4*)ctx;
    float4 c0 = ctx4[0 * 64 + lane];
    float4 c1 = ctx4[1 * 64 + lane];
    float4 c2 = ctx4[2 * 64 + lane];
    float4 c3 = ctx4[3 * 64 + lane];

    float4 a0 = {0.f,0.f,0.f,0.f}, a1 = {0.f,0.f,0.f,0.f};
    float4 a2 = {0.f,0.f,0.f,0.f}, a3 = {0.f,0.f,0.f,0.f};
    float m = -INFINITY, l = 0.0f;

    const float4* hp = (const float4*)hs + ((size_t)b * T + t0) * (D / 4);
    const int*    mp = mask + (size_t)b * T + t0;

    for (int i = 0; i < tokensPerWave; ++i) {
        const float4* row = hp + (size_t)i * (D / 4);
        float4 h0 = row[0 * 64 + lane];
        float4 h1 = row[1 * 64 + lane];
        float4 h2 = row[2 * 64 + lane];
        float4 h3 = row[3 * 64 + lane];

        float p = 0.0f;
        p = fmaf(h0.x, c0.x, p); p = fmaf(h0.y, c0.y, p);
        p = fmaf(h0.z, c0.z, p); p = fmaf(h0.w, c0.w, p);
        p = fmaf(h1.x, c1.x, p); p = fmaf(h1.y, c1.y, p);
        p = fmaf(h1.z, c1.z, p); p = fmaf(h1.w, c1.w, p);
        p = fmaf(h2.x, c2.x, p); p = fmaf(h2.y, c2.y, p);
        p = fmaf(h2.z, c2.z, p); p = fmaf(h2.w, c2.w, p);
        p = fmaf(h3.x, c3.x, p); p = fmaf(h3.y, c3.y, p);
        p = fmaf(h3.z, c3.z, p); p = fmaf(h3.w, c3.w, p);

        // full-wave butterfly reduce (64 lanes)
        #pragma unroll
        for (int off = 32; off > 0; off >>= 1) p += __shfl_xor(p, off);

        if (mp[i] != 0) {
            // online softmax update (branch is wave-uniform)
            float mn = fmaxf(m, p);
            float c  = __expf(m - mn);   // m = -inf first time -> c = 0
            float w  = __expf(p - mn);
            l = fmaf(l, c, w);
            a0.x = fmaf(a0.x, c, w * h0.x); a0.y = fmaf(a0.y, c, w * h0.y);
            a0.z = fmaf(a0.z, c, w * h0.z); a0.w = fmaf(a0.w, c, w * h0.w);
            a1.x = fmaf(a1.x, c, w * h1.x); a1.y = fmaf(a1.y, c, w * h1.y);
            a1.z = fmaf(a1.z, c, w * h1.z); a1.w = fmaf(a1.w, c, w * h1.w);
            a2.x = fmaf(a2.x, c, w * h2.x); a2.y = fmaf(a2.y, c, w * h2.y);
            a2.z = fmaf(a2.z, c, w * h2.z); a2.w = fmaf(a2.w, c, w * h2.w);
            a3.x = fmaf(a3.x, c, w * h3.x); a3.y = fmaf(a3.y, c, w * h3.y);
            a3.z = fmaf(a3.z, c, w * h3.z); a3.w = fmaf(a3.w, c, w * h3.w);
            m = mn;
        }
    }

    // ---- cross-wave merge in LDS ----
    __shared__ float  s_m[4];
    __shared__ float  s_lf[4];
    __shared__ float4 s_acc[4][256];   // 16 KB

    if (lane == 0) s_m[wave] = m;
    __syncthreads();
    float M = fmaxf(fmaxf(s_m[0], s_m[1]), fmaxf(s_m[2], s_m[3]));
    float f = (m == -INFINITY) ? 0.0f : __expf(m - M);
    if (lane == 0) s_lf[wave] = l * f;
    float4 t;
    t.x = a0.x * f; t.y = a0.y * f; t.z = a0.z * f; t.w = a0.w * f; s_acc[wave][0 * 64 + lane] = t;
    t.x = a1.x * f; t.y = a1.y * f; t.z = a1.z * f; t.w = a1.w * f; s_acc[wave][1 * 64 + lane] = t;
    t.x = a2.x * f; t.y = a2.y * f; t.z = a2.z * f; t.w = a2.w * f; s_acc[wave][2 * 64 + lane] = t;
    t.x = a3.x * f; t.y = a3.y * f; t.z = a3.z * f; t.w = a3.w * f; s_acc[wave][3 * 64 + lane] = t;
    __syncthreads();

    int tid = threadIdx.x;   // 256 threads, one float4 of D each
    float4 v0 = s_acc[0][tid], v1 = s_acc[1][tid], v2 = s_acc[2][tid], v3 = s_acc[3][tid];
    float4 r;
    r.x = (v0.x + v1.x) + (v2.x + v3.x);
    r.y = (v0.y + v1.y) + (v2.y + v3.y);
    r.z = (v0.z + v1.z) + (v2.z + v3.z);
    r.w = (v0.w + v1.w) + (v2.w + v3.w);

    float4* accs4 = (float4*)(accs + (size_t)bi * D);
    accs4[tid] = r;
    if (tid == 0) {
        ms[bi] = M;
        ls[bi] = (s_lf[0] + s_lf[1]) + (s_lf[2] + s_lf[3]);
    }
}

__global__ __launch_bounds__(256) void ap_combine(
    const float* __restrict__ accs, const float* __restrict__ ms,
    const float* __restrict__ ls, float* __restrict__ out, int numChunks)
{
    int b   = blockIdx.x;
    int tid = threadIdx.x;
    const float* mB = ms + (size_t)b * numChunks;
    const float* lB = ls + (size_t)b * numChunks;

    float M = -INFINITY;
    for (int c = 0; c < numChunks; ++c) M = fmaxf(M, mB[c]);
    float L = 0.0f;
    for (int c = 0; c < numChunks; ++c) {
        float mc = mB[c];
        float f  = (mc == -INFINITY) ? 0.0f : __expf(mc - M);
        L += lB[c] * f;
    }

    float rx = 0.f, ry = 0.f, rz = 0.f, rw = 0.f;
    const float4* accs4 = (const float4*)accs;
    for (int c = 0; c < numChunks; ++c) {
        float mc = mB[c];
        float f  = (mc == -INFINITY) ? 0.0f : __expf(mc - M);
        float4 v = accs4[((size_t)b * numChunks + c) * 256 + tid];
        rx = fmaf(v.x, f, rx); ry = fmaf(v.y, f, ry);
        rz = fmaf(v.z, f, rz); rw = fmaf(v.w, f, rw);
    }
    float inv = 1.0f / L;
    float4 o; o.x = rx * inv; o.y = ry * inv; o.z = rz * inv; o.w = rw * inv;
    ((float4*)out)[(size_t)b * 256 + tid] = o;
}

extern "C" void kernel_launch(void* const* d_in, const int* in_sizes, int n_in,
                              void* d_out, int out_size, void* d_ws, size_t ws_size,
                              hipStream_t stream)
{
    const float* hs   = (const float*)d_in[0];
    const int*   mask = (const int*)d_in[1];
    const float* ctx  = (const float*)d_in[2];

    const int D = 1024;
    int B = out_size / D;          // 16
    int T = in_sizes[1] / B;       // 4096

    // pick chunking: 64 chunks/b -> 1024 blocks (4/CU), shrink if ws too small
    int blocksPerB = 64;
    while (blocksPerB > 1 &&
           ((T % (4 * blocksPerB)) != 0 ||
            (size_t)B * blocksPerB * (size_t)(D + 2) * sizeof(float) > ws_size))
        blocksPerB >>= 1;
    int tokensPerWave = T / (4 * blocksPerB);
    int numP = B * blocksPerB;

    float* accs = (float*)d_ws;
    float* ms   = accs + (size_t)numP * D;
    float* ls   = ms + numP;

    ap_partial<<<numP, 256, 0, stream>>>(hs, mask, ctx, accs, ms, ls,
                                         T, blocksPerB, tokensPerWave);
    ap_combine<<<B, 256, 0, stream>>>(accs, ms, ls, (float*)d_out, blocksPerB);
}